// Round 14
// baseline (246.916 us; speedup 1.0000x reference)
//
#include <hip/hip_runtime.h>
#include <math.h>

#define B_    4096
#define N_    10
#define DIN_  32
#define D_    128
#define PHI_  256
#define RHO_  128
#define L_    3
#define EPS_  1e-5f

// ---- fp16 helpers (bits in short) ----
__device__ __forceinline__ short f2hs(float f) {            // f32 -> fp16 RNE
    union { _Float16 h; short s; } u;
    u.h = (_Float16)f;
    return u.s;
}
__device__ __forceinline__ float hs2f(short s) {
    union { _Float16 h; short s; } u;
    u.s = s;
    return (float)u.h;
}

typedef short    s16x8 __attribute__((ext_vector_type(8)));
typedef _Float16 h16x8 __attribute__((ext_vector_type(8)));
typedef float    f32x4 __attribute__((ext_vector_type(4)));
typedef float    v2f   __attribute__((ext_vector_type(2)));

__device__ __forceinline__ h16x8 ld8h(const short* p) {
    union { s16x8 s; h16x8 h; } u;
    u.s = *(const s16x8*)p;
    return u.h;
}
__device__ __forceinline__ h16x8 cvt8(const float* p) {     // 8 f32 -> 8 fp16
    f32x4 x0 = *(const f32x4*)p;
    f32x4 x1 = *(const f32x4*)(p + 4);
    h16x8 a;
    a[0]=(_Float16)x0[0]; a[1]=(_Float16)x0[1]; a[2]=(_Float16)x0[2]; a[3]=(_Float16)x0[3];
    a[4]=(_Float16)x1[0]; a[5]=(_Float16)x1[1]; a[6]=(_Float16)x1[2]; a[7]=(_Float16)x1[3];
    return a;
}

__device__ __forceinline__ v2f splat2(float s) { v2f r; r.x = s; r.y = s; return r; }
__device__ __forceinline__ v2f fma2(v2f a, v2f b, v2f c) { return __builtin_elementwise_fma(a, b, c); }

// ---- d_ws layout (fp16 elements). Fragment unit = 64 lanes x 8 el = 512 el.
// For matrix W[K][N]: frag (nt,ks) at ((nt*KS+ks)*64+lane)*8, lane holds
// W[ks*32+(lane>>4)*8+j][nt*16+(lane&15)], j=0..7  (B-operand layout, 16x16x32)
#define WS_WE1 0
#define WS_WE2 4096
#define WS_RGW 20480
#define WS_RGR 118784
#define WS_L1  167936
#define WS_L2  217088
#define WS_P1  266240
#define WS_P2  299008
#define WS_R1  364544

// ================= prep kernel: fp32 weights -> fp16 B-fragments ==========
// 256-thread blocks, 4 logical fragment-tasks per block.
__global__ __launch_bounds__(256)
void prep_weights(const float* __restrict__ We1, const float* __restrict__ We2,
                  const float* __restrict__ rgw, const float* __restrict__ rgr,
                  const float* __restrict__ l1w, const float* __restrict__ l2w,
                  const float* __restrict__ p1w, const float* __restrict__ p2w,
                  const float* __restrict__ r1w, short* __restrict__ ws)
{
    int bi = blockIdx.x * 4 + (threadIdx.x >> 6);   // virtual 0..775
    int l  = threadIdx.x & 63;
    const float* src; int KS, Nw, dstOff, tt;
    if      (bi <   8) { src = We1; KS = 1; Nw = 128; dstOff = WS_WE1; tt = bi; }
    else if (bi <  40) { src = We2; KS = 4; Nw = 128; dstOff = WS_WE2; tt = bi - 8; }
    else if (bi < 232) { int m = (bi - 40) >> 5;  src = rgw + m * 16384; KS = 4; Nw = 128; dstOff = WS_RGW + m * 16384; tt = (bi - 40)  & 31; }
    else if (bi < 328) { int m = (bi - 232) >> 5; src = rgr + m * 16384; KS = 4; Nw = 128; dstOff = WS_RGR + m * 16384; tt = (bi - 232) & 31; }
    else if (bi < 424) { int m = (bi - 328) >> 5; src = l1w + m * 16384; KS = 4; Nw = 128; dstOff = WS_L1  + m * 16384; tt = (bi - 328) & 31; }
    else if (bi < 520) { int m = (bi - 424) >> 5; src = l2w + m * 16384; KS = 4; Nw = 128; dstOff = WS_L2  + m * 16384; tt = (bi - 424) & 31; }
    else if (bi < 584) { src = p1w; KS = 4; Nw = 256; dstOff = WS_P1; tt = bi - 520; }
    else if (bi < 712) { src = p2w; KS = 8; Nw = 256; dstOff = WS_P2; tt = bi - 584; }
    else               { src = r1w; KS = 8; Nw = 128; dstOff = WS_R1; tt = bi - 712; }
    int nt = tt / KS, ks = tt - nt * KS;
    int kbase = ks * 32 + (l >> 4) * 8;
    int col   = nt * 16 + (l & 15);
    union { short s[8]; int4 v; } u;
#pragma unroll
    for (int j = 0; j < 8; ++j)
        u.s[j] = f2hs(src[(size_t)(kbase + j) * Nw + col]);
    *(int4*)(ws + dstOff + ((size_t)tt * 64 + l) * 8) = u.v;
}

// ================= main kernel: 1 block (4 waves) = 2 graphs ===============
// r14 change (one variable): s_setprio(1)/(0) around each 16-MFMA cluster
// (T5). Regime: ~5 independent blocks/CU at uncorrelated phases — the
// configuration where setprio paid on attn (m191), not the lockstep-null
// GEMM case (m190). Pre-commit: null -> revert, structure exhausted.
// r13 (kept): full unroll of RGCN m-loop + phi half-loops — cross-pass
// weight-load hoisting, gcn_main 155->147 us.
// Burst-load matmuls; verified r9-r13: VGPR 80, zero scratch (WRITE 64 KB).
// A-operand layout: lane holds A[m=lane&15][k=(lane>>4)*8+j]; rows >=10 clamped
// C/D layout: col = lane&15, row = (lane>>4)*4 + reg

#define MFMA16(a, b, c) __builtin_amdgcn_mfma_f32_16x16x32_f16(a, b, c, 0, 0, 0)

struct A4 { f32x4 p, q, r, s; };   // p=(g0,nt0) q=(g0,nt1) r=(g1,nt0) s=(g1,nt1)

__device__ __forceinline__ A4 a4init(const float* __restrict__ bias, int c16) {
    float b0 = bias[c16], b1 = bias[16 + c16];
    A4 c;
    c.p = (f32x4){b0, b0, b0, b0};
    c.q = (f32x4){b1, b1, b1, b1};
    c.r = c.p;
    c.s = c.q;
    return c;
}
__device__ __forceinline__ A4 a4zero() {
    A4 c;
    c.p = (f32x4){0.f, 0.f, 0.f, 0.f};
    c.q = c.p; c.r = c.p; c.s = c.p;
    return c;
}

// dual-graph, 2-tile matmul, fp16 A from LDS; burst-load 4-ks chunks
template<int KS>
__device__ __forceinline__ A4 mm2q_a16(const short* __restrict__ Wf,
                                       const short* __restrict__ A0, const short* __restrict__ A1,
                                       int ldA, int mrow, int q, int l, A4 c) {
    static_assert(KS % 4 == 0, "KS must be a multiple of 4");
    const short* ap0 = A0 + mrow * ldA + q * 8;
    const short* ap1 = A1 + mrow * ldA + q * 8;
    const short* wp  = Wf + (size_t)l * 8;
#pragma unroll
    for (int kc = 0; kc < KS; kc += 4) {
        h16x8 fa0[4], fa1[4], fb0[4], fb1[4];
#pragma unroll
        for (int k = 0; k < 4; ++k) {
            fa0[k] = ld8h(ap0 + (kc + k) * 32);
            fa1[k] = ld8h(ap1 + (kc + k) * 32);
            fb0[k] = ld8h(wp + (size_t)(kc + k) * 512);
            fb1[k] = ld8h(wp + (size_t)(KS + kc + k) * 512);
        }
        __builtin_amdgcn_s_setprio(1);
#pragma unroll
        for (int k = 0; k < 4; ++k) {
            c.p = MFMA16(fa0[k], fb0[k], c.p);
            c.r = MFMA16(fa1[k], fb0[k], c.r);
            c.q = MFMA16(fa0[k], fb1[k], c.q);
            c.s = MFMA16(fa1[k], fb1[k], c.s);
        }
        __builtin_amdgcn_s_setprio(0);
    }
    return c;
}

// dual-graph, 2-tile matmul, fp32 A from LDS (converted per k-slice); burst
template<int KS>
__device__ __forceinline__ A4 mm2q_a32(const short* __restrict__ Wf,
                                       const float* __restrict__ A0, const float* __restrict__ A1,
                                       int ldA, int mrow, int q, int l, A4 c) {
    static_assert(KS % 4 == 0, "KS must be a multiple of 4");
    const float* ap0 = A0 + mrow * ldA + q * 8;
    const float* ap1 = A1 + mrow * ldA + q * 8;
    const short* wp  = Wf + (size_t)l * 8;
#pragma unroll
    for (int kc = 0; kc < KS; kc += 4) {
        h16x8 fa0[4], fa1[4], fb0[4], fb1[4];
#pragma unroll
        for (int k = 0; k < 4; ++k) {
            fa0[k] = cvt8(ap0 + (kc + k) * 32);
            fa1[k] = cvt8(ap1 + (kc + k) * 32);
            fb0[k] = ld8h(wp + (size_t)(kc + k) * 512);
            fb1[k] = ld8h(wp + (size_t)(KS + kc + k) * 512);
        }
        __builtin_amdgcn_s_setprio(1);
#pragma unroll
        for (int k = 0; k < 4; ++k) {
            c.p = MFMA16(fa0[k], fb0[k], c.p);
            c.r = MFMA16(fa1[k], fb0[k], c.r);
            c.q = MFMA16(fa0[k], fb1[k], c.q);
            c.s = MFMA16(fa1[k], fb1[k], c.s);
        }
        __builtin_amdgcn_s_setprio(0);
    }
    return c;
}

#define HLD 132   // Hf row stride (f32)
#define SLD 392   // staging row stride (fp16)

// store one graph's 2 tiles (by value) into staging LDS, rows >= 10 dropped
template<bool RELU>
__device__ __forceinline__ void st2(f32x4 u, f32x4 v, short* __restrict__ dst, int q, int c16) {
#pragma unroll
    for (int i = 0; i < 4; ++i) {
        int r = q * 4 + i;
        if (r < 10) {
            float a = u[i], b = v[i];
            if (RELU) { a = fmaxf(a, 0.f); b = fmaxf(b, 0.f); }
            dst[r * SLD + c16]      = f2hs(a);
            dst[r * SLD + 16 + c16] = f2hs(b);
        }
    }
}

// masked column-sum epilogue for ONE phi2 tile (by value)
__device__ __forceinline__ void colsum1(f32x4 v4, const float* __restrict__ hmf,
                                        const float* __restrict__ awf,
                                        short* __restrict__ rho, int tt, int q, int c16, int l) {
    float v0 = fmaxf(v4[0], 0.f), v1 = fmaxf(v4[1], 0.f);
    float v2 = fmaxf(v4[2], 0.f), v3 = fmaxf(v4[3], 0.f);
    float hp = hmf[q * 4 + 0] * v0 + hmf[q * 4 + 1] * v1 + hmf[q * 4 + 2] * v2 + hmf[q * 4 + 3] * v3;
    float ap = awf[q * 4 + 0] * v0 + awf[q * 4 + 1] * v1 + awf[q * 4 + 2] * v2 + awf[q * 4 + 3] * v3;
    hp += __shfl_xor(hp, 16); hp += __shfl_xor(hp, 32);
    ap += __shfl_xor(ap, 16); ap += __shfl_xor(ap, 32);
    if (l < 16) {
        rho[tt * 16 + l]       = f2hs(hp);
        rho[256 + tt * 16 + l] = f2hs(ap);
    }
}

// rho epilogue for ONE graph (by value)
__device__ __forceinline__ void rhoepi1(f32x4 t0, f32x4 t1, const float* __restrict__ r2w,
                                        int wv, int q, int c16, int l, float* __restrict__ dSg) {
    float d = 0.f;
    if (q == 0) {
        d = (fmaxf(t0[0], 0.f) - fmaxf(t0[1], 0.f)) * r2w[(wv * 2 + 0) * 16 + c16];
        d = fmaf(fmaxf(t1[0], 0.f) - fmaxf(t1[1], 0.f), r2w[(wv * 2 + 1) * 16 + c16], d);
    }
#pragma unroll
    for (int off = 32; off > 0; off >>= 1) d += __shfl_xor(d, off);
    if (l == 0) dSg[wv] = d;
}

// waves_per_eu(2,5): r9 proved this kills scratch at VGPR<=102 budget.
__global__ __attribute__((amdgpu_waves_per_eu(2, 5))) __launch_bounds__(256)
void gcn_main(const float* __restrict__ A, const float* __restrict__ X,
              const int* __restrict__ home_mask,
              const float* __restrict__ be1, const float* __restrict__ be2,
              const float* __restrict__ rgcn_b,
              const float* __restrict__ l1b, const float* __restrict__ l2b,
              const float* __restrict__ ln_g, const float* __restrict__ ln_b,
              const float* __restrict__ p1b, const float* __restrict__ p2b,
              const float* __restrict__ r1b, const float* __restrict__ r2w,
              const short* __restrict__ ws, float* __restrict__ out)
{
    const int b   = blockIdx.x;        // graph pair: graphs 2b, 2b+1
    const int tid = threadIdx.x;       // 0..255
    const int wv  = tid >> 6;          // wave 0..3
    const int l   = tid & 63;          // lane
    const int q   = l >> 4;
    const int c16 = l & 15;
    const int mrow = (c16 < 10) ? c16 : 9;

    // per-graph state (31.2 KB total)
    __shared__ __align__(16) float HfS[2][N_ * HLD];   // residual H, fp32
    __shared__ __align__(16) short StS[2][N_ * SLD];   // staging: HW0|HW1|HWr / LN|hidden / phi
    __shared__ __align__(16) short RhoS[2][512];       // [hs ; aws] fp16
    __shared__ float AsS[2][100];                      // signed A
    __shared__ float C0S[2][100], C1S[2][100];         // |A|·D0·M0^T etc (layer-invariant)
    __shared__ float invc0S[2][N_], invc1S[2][N_], rsAS[2][N_];
    __shared__ float hmfS[2][16], awfS[2][16];
    __shared__ float dS[8];

    // ---- phase 0: stage A (signed) + masks + embed1 ----
    if (tid < 200) {
        int g = tid / 100, e = tid - g * 100;
        AsS[g][e] = A[(size_t)(2 * b + g) * 100 + e];
    }
    if (tid < 32) {
        int g = tid >> 4, idx = tid & 15;
        float hm = 0.f, aw = 0.f;
        if (idx < 10) { hm = (float)home_mask[(2 * b + g) * N_ + idx]; aw = 1.f - hm; }
        hmfS[g][idx] = hm; awfS[g][idx] = aw;
    }
    {   // embed1: H1 = relu(X@We1 + be1) -> St[g][0:128]
        A4 c = a4init(be1 + wv * 32, c16);
        h16x8 a0 = cvt8(X + (size_t)(2 * b + 0) * (N_ * DIN_) + mrow * DIN_ + q * 8);
        h16x8 a1 = cvt8(X + (size_t)(2 * b + 1) * (N_ * DIN_) + mrow * DIN_ + q * 8);
        h16x8 b0 = ld8h(ws + WS_WE1 + ((size_t)(wv * 2 + 0) * 64 + l) * 8);
        h16x8 b1 = ld8h(ws + WS_WE1 + ((size_t)(wv * 2 + 1) * 64 + l) * 8);
        c.p = MFMA16(a0, b0, c.p);
        c.r = MFMA16(a1, b0, c.r);
        c.q = MFMA16(a0, b1, c.q);
        c.s = MFMA16(a1, b1, c.s);
        st2<true>(c.p, c.q, StS[0] + wv * 32, q, c16);
        st2<true>(c.r, c.s, StS[1] + wv * 32, q, c16);
    }
    __syncthreads();

    // ---- phase 1: invc + rsA (VALU) + embed2 (MFMA) ----
    if (tid < 20) {
        int g = tid / 10, j = tid - g * 10;
        float c1 = 0.f;
#pragma unroll
        for (int i = 0; i < 10; ++i) c1 += (AsS[g][i * 10 + j] > 0.f) ? 1.f : 0.f;
        invc1S[g][j] = 1.f / fmaxf(c1, 1.f);
        invc0S[g][j] = 1.f / fmaxf(10.f - c1, 1.f);
        float r = 0.f;
#pragma unroll
        for (int k = 0; k < 10; ++k) r += fabsf(AsS[g][j * 10 + k]);
        rsAS[g][j] = r;
    }
    {   // embed2: H = H1@We2 + be2 -> Hf (fp32)
        A4 c = a4init(be2 + wv * 32, c16);
        c = mm2q_a16<4>(ws + WS_WE2 + (size_t)wv * 4096, StS[0], StS[1], SLD, mrow, q, l, c);
#pragma unroll
        for (int i = 0; i < 4; ++i) {
            int r = q * 4 + i;
            if (r < 10) {
                HfS[0][r * HLD + wv * 32 + c16]      = c.p[i];
                HfS[0][r * HLD + wv * 32 + 16 + c16] = c.q[i];
                HfS[1][r * HLD + wv * 32 + c16]      = c.r[i];
                HfS[1][r * HLD + wv * 32 + 16 + c16] = c.s[i];
            }
        }
    }
    __syncthreads();

    // ---- phase 2: coefficient matrices (layer-invariant):
    //   agg[i] = sum_k C0[i,k]·HW0[k] + C1[i,k]·HW1[k] + |A[i,k]|·HWr[k] + rsA[i]·b
    if (tid < 200) {
        int g = tid / 100, e = tid - g * 100;
        int i = e / 10, k = e - i * 10;
        const float* As = AsS[g];
        float c0 = 0.f, c1 = 0.f;
#pragma unroll
        for (int j = 0; j < 10; ++j) {
            float aij = fabsf(As[i * 10 + j]);
            if (As[k * 10 + j] > 0.f) c1 += aij * invc1S[g][j];
            else                      c0 += aij * invc0S[g][j];
        }
        C0S[g][e] = c0; C1S[g][e] = c1;
    }
    __syncthreads();

    const v2f lg2 = *(const v2f*)(ln_g + 2 * l);
    const v2f lb2 = *(const v2f*)(ln_b + 2 * l);

    // ---- layers ----
    for (int ll = 0; ll < L_; ++ll) {
        // RGCN matmuls, 3 passes: HW0|HW1|HWr -> St[g][m*128 ..].
        // FULL unroll (r13): no barrier between passes; scheduler hoists
        // pass m+1's weight loads under pass m's MFMAs.
#pragma unroll
        for (int m = 0; m < 3; ++m) {
            const short* Wf;
            if      (m == 0) Wf = ws + WS_RGW + (size_t)(ll * 2 + 0) * 16384 + (size_t)wv * 4096;
            else if (m == 1) Wf = ws + WS_RGW + (size_t)(ll * 2 + 1) * 16384 + (size_t)wv * 4096;
            else             Wf = ws + WS_RGR + (size_t)ll * 16384 + (size_t)wv * 4096;
            A4 c = a4zero();
            c = mm2q_a32<4>(Wf, HfS[0], HfS[1], HLD, mrow, q, l, c);
            st2<false>(c.p, c.q, StS[0] + m * 128 + wv * 32, q, c16);
            st2<false>(c.r, c.s, StS[1] + m * 128 + wv * 32, q, c16);
        }
        __syncthreads();
        // combine + LN + relu (VALU): wave wv owns tasks t = wv+4s; named results
        {
            v2f rb2 = *(const v2f*)(rgcn_b + ll * D_ + 2 * l);
            auto lnTask = [&](int t) -> short2 {
                int g = (t >= 10) ? 1 : 0, i = t - g * 10;
                const short* St = StS[g];
                const float* C0 = C0S[g] + i * 10;
                const float* C1 = C1S[g] + i * 10;
                const float* As = AsS[g] + i * 10;
                v2f ag = splat2(rsAS[g][i]) * rb2;
#pragma unroll
                for (int j = 0; j < 10; ++j) {
                    short2 h0 = *(const short2*)(St + j * SLD + 2 * l);
                    short2 h1 = *(const short2*)(St + j * SLD + 128 + 2 * l);
                    short2 hr = *(const short2*)(St + j * SLD + 256 + 2 * l);
                    v2f v0; v0.x = hs2f(h0.x); v0.y = hs2f(h0.y);
                    v2f v1; v1.x = hs2f(h1.x); v1.y = hs2f(h1.y);
                    v2f vr; vr.x = hs2f(hr.x); vr.y = hs2f(hr.y);
                    ag = fma2(splat2(C0[j]), v0, ag);
                    ag = fma2(splat2(C1[j]), v1, ag);
                    ag = fma2(splat2(fabsf(As[j])), vr, ag);
                }
                float sm = ag.x + ag.y;
                float ss = fmaf(ag.x, ag.x, ag.y * ag.y);
#pragma unroll
                for (int off = 32; off > 0; off >>= 1) {
                    sm += __shfl_xor(sm, off);
                    ss += __shfl_xor(ss, off);
                }
                float mu   = sm * (1.f / 128.f);
                float var  = ss * (1.f / 128.f) - mu * mu;
                float rstd = rsqrtf(var + EPS_);
                v2f v = fma2((ag - splat2(mu)) * splat2(rstd), lg2, lb2);
                short2 o;
                o.x = f2hs(fmaxf(v.x, 0.f));
                o.y = f2hs(fmaxf(v.y, 0.f));
                return o;
            };
            short2 ln0 = lnTask(wv);
            short2 ln1 = lnTask(wv + 4);
            short2 ln2 = lnTask(wv + 8);
            short2 ln3 = lnTask(wv + 12);
            short2 ln4 = lnTask(wv + 16);
            __syncthreads();                   // all HW* reads done
            auto stTask = [&](int t, short2 v) {
                int g = (t >= 10) ? 1 : 0, i = t - g * 10;
                *(short2*)(StS[g] + i * SLD + 2 * l) = v;   // LNout -> cols 0:128
            };
            stTask(wv, ln0);
            stTask(wv + 4, ln1);
            stTask(wv + 8, ln2);
            stTask(wv + 12, ln3);
            stTask(wv + 16, ln4);
        }
        __syncthreads();
        // MLP1: relu(LNout @ l1w + l1b): reads St[0:128], writes St[128:256]
        {
            A4 c = a4init(l1b + ll * D_ + wv * 32, c16);
            c = mm2q_a16<4>(ws + WS_L1 + (size_t)ll * 16384 + (size_t)wv * 4096,
                            StS[0], StS[1], SLD, mrow, q, l, c);
            st2<true>(c.p, c.q, StS[0] + 128 + wv * 32, q, c16);
            st2<true>(c.r, c.s, StS[1] + 128 + wv * 32, q, c16);
        }
        __syncthreads();
        // MLP2: hidden @ l2w + l2b: reads St[128:256], Hf += result
        {
            A4 c = a4init(l2b + ll * D_ + wv * 32, c16);
            c = mm2q_a16<4>(ws + WS_L2 + (size_t)ll * 16384 + (size_t)wv * 4096,
                            StS[0] + 128, StS[1] + 128, SLD, mrow, q, l, c);
#pragma unroll
            for (int i = 0; i < 4; ++i) {
                int r = q * 4 + i;
                if (r < 10) {
                    HfS[0][r * HLD + wv * 32 + c16]      += c.p[i];
                    HfS[0][r * HLD + wv * 32 + 16 + c16] += c.q[i];
                    HfS[1][r * HLD + wv * 32 + c16]      += c.r[i];
                    HfS[1][r * HLD + wv * 32 + 16 + c16] += c.s[i];
                }
            }
        }
        __syncthreads();
    }

    // ---- phi1: relu(H @ p1w + p1b) -> St[g][0:256]; 2 passes of 2 tiles ----
#pragma unroll
    for (int half = 0; half < 2; ++half) {
        const int nt0 = 4 * wv + 2 * half;
        A4 c = a4init(p1b + nt0 * 16, c16);
        c = mm2q_a32<4>(ws + WS_P1 + (size_t)nt0 * 2048, HfS[0], HfS[1], HLD, mrow, q, l, c);
        st2<true>(c.p, c.q, StS[0] + nt0 * 16, q, c16);
        st2<true>(c.r, c.s, StS[1] + nt0 * 16, q, c16);
    }
    __syncthreads();
    // ---- phi2 + masked column sums -> RhoS[g]; 2 passes of 2 tiles ----
#pragma unroll
    for (int half = 0; half < 2; ++half) {
        const int nt0 = 4 * wv + 2 * half;
        A4 c = a4init(p2b + nt0 * 16, c16);
        c = mm2q_a16<8>(ws + WS_P2 + (size_t)nt0 * 4096, StS[0], StS[1], SLD, mrow, q, l, c);
        colsum1(c.p, hmfS[0], awfS[0], RhoS[0], nt0,     q, c16, l);
        colsum1(c.q, hmfS[0], awfS[0], RhoS[0], nt0 + 1, q, c16, l);
        colsum1(c.r, hmfS[1], awfS[1], RhoS[1], nt0,     q, c16, l);
        colsum1(c.s, hmfS[1], awfS[1], RhoS[1], nt0 + 1, q, c16, l);
    }
    __syncthreads();
    // ---- rho: relu([hs;aws] @ r1w + r1b) @ r2w; antisym difference ----
    {
        A4 c = a4init(r1b + wv * 32, c16);
        const int rr = (c16 < 2) ? c16 : 0;
        c = mm2q_a16<8>(ws + WS_R1 + (size_t)wv * 8192, RhoS[0], RhoS[1], 256, rr, q, l, c);
        rhoepi1(c.p, c.q, r2w, wv, q, c16, l, dS);       // graph 0
        rhoepi1(c.r, c.s, r2w, wv, q, c16, l, dS + 4);   // graph 1
    }
    __syncthreads();
    if (tid < 2)
        out[2 * b + tid] = 0.5f + 0.5f * tanhf(dS[tid * 4] + dS[tid * 4 + 1] +
                                               dS[tid * 4 + 2] + dS[tid * 4 + 3]);
}

extern "C" void kernel_launch(void* const* d_in, const int* in_sizes, int n_in,
                              void* d_out, int out_size, void* d_ws, size_t ws_size,
                              hipStream_t stream) {
    const float* A         = (const float*)d_in[0];
    const float* X         = (const float*)d_in[1];
    const int*   home_mask = (const int*)  d_in[2];
    const float* We1       = (const float*)d_in[3];
    const float* be1       = (const float*)d_in[4];
    const float* We2       = (const float*)d_in[5];
    const float* be2       = (const float*)d_in[6];
    const float* rgcn_w    = (const float*)d_in[7];
    const float* rgcn_root = (const float*)d_in[8];
    const float* rgcn_b    = (const float*)d_in[9];
    const float* l1w       = (const float*)d_in[10];
    const float* l1b       = (const float*)d_in[11];
    const float* l2w       = (const float*)d_in[12];
    const float* l2b       = (const float*)d_in[13];
    const float* ln_g      = (const float*)d_in[14];
    const float* ln_b      = (const float*)d_in[15];
    const float* p1w       = (const float*)d_in[16];
    const float* p1b       = (const float*)d_in[17];
    const float* p2w       = (const float*)d_in[18];
    const float* p2b       = (const float*)d_in[19];
    const float* r1w       = (const float*)d_in[20];
    const float* r1b       = (const float*)d_in[21];
    const float* r2w       = (const float*)d_in[22];

    short* ws = (short*)d_ws;

    prep_weights<<<194, 256, 0, stream>>>(We1, We2, rgcn_w, rgcn_root,
                                          l1w, l2w, p1w, p2w, r1w, ws);
    gcn_main<<<B_ / 2, 256, 0, stream>>>(A, X, home_mask, be1, be2, rgcn_b,
                                         l1b, l2b, ln_g, ln_b, p1b, p2b,
                                         r1b, r2w, ws, (float*)d_out);
}

// Round 15
// 232.140 us; speedup vs baseline: 1.0637x; 1.0637x over previous
//
#include <hip/hip_runtime.h>
#include <math.h>

#define B_    4096
#define N_    10
#define DIN_  32
#define D_    128
#define PHI_  256
#define RHO_  128
#define L_    3
#define EPS_  1e-5f

// ---- fp16 helpers (bits in short) ----
__device__ __forceinline__ short f2hs(float f) {            // f32 -> fp16 RNE
    union { _Float16 h; short s; } u;
    u.h = (_Float16)f;
    return u.s;
}
__device__ __forceinline__ float hs2f(short s) {
    union { _Float16 h; short s; } u;
    u.s = s;
    return (float)u.h;
}

typedef short    s16x8 __attribute__((ext_vector_type(8)));
typedef _Float16 h16x8 __attribute__((ext_vector_type(8)));
typedef float    f32x4 __attribute__((ext_vector_type(4)));
typedef float    v2f   __attribute__((ext_vector_type(2)));

__device__ __forceinline__ h16x8 ld8h(const short* p) {
    union { s16x8 s; h16x8 h; } u;
    u.s = *(const s16x8*)p;
    return u.h;
}
__device__ __forceinline__ h16x8 cvt8(const float* p) {     // 8 f32 -> 8 fp16
    f32x4 x0 = *(const f32x4*)p;
    f32x4 x1 = *(const f32x4*)(p + 4);
    h16x8 a;
    a[0]=(_Float16)x0[0]; a[1]=(_Float16)x0[1]; a[2]=(_Float16)x0[2]; a[3]=(_Float16)x0[3];
    a[4]=(_Float16)x1[0]; a[5]=(_Float16)x1[1]; a[6]=(_Float16)x1[2]; a[7]=(_Float16)x1[3];
    return a;
}

__device__ __forceinline__ v2f splat2(float s) { v2f r; r.x = s; r.y = s; return r; }
__device__ __forceinline__ v2f fma2(v2f a, v2f b, v2f c) { return __builtin_elementwise_fma(a, b, c); }

// ---- d_ws layout (fp16 elements). Fragment unit = 64 lanes x 8 el = 512 el.
// For matrix W[K][N]: frag (nt,ks) at ((nt*KS+ks)*64+lane)*8, lane holds
// W[ks*32+(lane>>4)*8+j][nt*16+(lane&15)], j=0..7  (B-operand layout, 16x16x32)
#define WS_WE1 0
#define WS_WE2 4096
#define WS_RGW 20480
#define WS_RGR 118784
#define WS_L1  167936
#define WS_L2  217088
#define WS_P1  266240
#define WS_P2  299008
#define WS_R1  364544

// ================= prep kernel: fp32 weights -> fp16 B-fragments ==========
// 256-thread blocks, 4 logical fragment-tasks per block.
__global__ __launch_bounds__(256)
void prep_weights(const float* __restrict__ We1, const float* __restrict__ We2,
                  const float* __restrict__ rgw, const float* __restrict__ rgr,
                  const float* __restrict__ l1w, const float* __restrict__ l2w,
                  const float* __restrict__ p1w, const float* __restrict__ p2w,
                  const float* __restrict__ r1w, short* __restrict__ ws)
{
    int bi = blockIdx.x * 4 + (threadIdx.x >> 6);   // virtual 0..775
    int l  = threadIdx.x & 63;
    const float* src; int KS, Nw, dstOff, tt;
    if      (bi <   8) { src = We1; KS = 1; Nw = 128; dstOff = WS_WE1; tt = bi; }
    else if (bi <  40) { src = We2; KS = 4; Nw = 128; dstOff = WS_WE2; tt = bi - 8; }
    else if (bi < 232) { int m = (bi - 40) >> 5;  src = rgw + m * 16384; KS = 4; Nw = 128; dstOff = WS_RGW + m * 16384; tt = (bi - 40)  & 31; }
    else if (bi < 328) { int m = (bi - 232) >> 5; src = rgr + m * 16384; KS = 4; Nw = 128; dstOff = WS_RGR + m * 16384; tt = (bi - 232) & 31; }
    else if (bi < 424) { int m = (bi - 328) >> 5; src = l1w + m * 16384; KS = 4; Nw = 128; dstOff = WS_L1  + m * 16384; tt = (bi - 328) & 31; }
    else if (bi < 520) { int m = (bi - 424) >> 5; src = l2w + m * 16384; KS = 4; Nw = 128; dstOff = WS_L2  + m * 16384; tt = (bi - 424) & 31; }
    else if (bi < 584) { src = p1w; KS = 4; Nw = 256; dstOff = WS_P1; tt = bi - 520; }
    else if (bi < 712) { src = p2w; KS = 8; Nw = 256; dstOff = WS_P2; tt = bi - 584; }
    else               { src = r1w; KS = 8; Nw = 128; dstOff = WS_R1; tt = bi - 712; }
    int nt = tt / KS, ks = tt - nt * KS;
    int kbase = ks * 32 + (l >> 4) * 8;
    int col   = nt * 16 + (l & 15);
    union { short s[8]; int4 v; } u;
#pragma unroll
    for (int j = 0; j < 8; ++j)
        u.s[j] = f2hs(src[(size_t)(kbase + j) * Nw + col]);
    *(int4*)(ws + dstOff + ((size_t)tt * 64 + l) * 8) = u.v;
}

// ================= main kernel: 1 block (4 waves) = 2 graphs ===============
// FINAL (r15 = r13 verbatim, session best 232.9 us). Verdicts from this
// session: scratch elimination via burst+by-value+waves_per_eu (+, r9);
// prep 256-thread blocks (+, r9); full unroll of barrier-free pass loops
// (+, r13: cross-pass weight-load hoisting, 155->147 us); occupancy knobs
// (0, r10); LDS-op reduction via readlane/fp16-shadow (-, r11); s_setprio
// around MFMA bursts (-, r14: VGPR 80->92, occupancy -28%, bank conflicts
// +73%). Latency-bound at ~37% VALU / ~15% MFMA; next step would be a
// 32x32-MFMA 3-graph repack (full rewrite, not attempted).
// Burst-load matmuls; verified: VGPR 80, zero scratch (WRITE 64 KB).
// A-operand layout: lane holds A[m=lane&15][k=(lane>>4)*8+j]; rows >=10 clamped
// C/D layout: col = lane&15, row = (lane>>4)*4 + reg

#define MFMA16(a, b, c) __builtin_amdgcn_mfma_f32_16x16x32_f16(a, b, c, 0, 0, 0)

struct A4 { f32x4 p, q, r, s; };   // p=(g0,nt0) q=(g0,nt1) r=(g1,nt0) s=(g1,nt1)

__device__ __forceinline__ A4 a4init(const float* __restrict__ bias, int c16) {
    float b0 = bias[c16], b1 = bias[16 + c16];
    A4 c;
    c.p = (f32x4){b0, b0, b0, b0};
    c.q = (f32x4){b1, b1, b1, b1};
    c.r = c.p;
    c.s = c.q;
    return c;
}
__device__ __forceinline__ A4 a4zero() {
    A4 c;
    c.p = (f32x4){0.f, 0.f, 0.f, 0.f};
    c.q = c.p; c.r = c.p; c.s = c.p;
    return c;
}

// dual-graph, 2-tile matmul, fp16 A from LDS; burst-load 4-ks chunks
template<int KS>
__device__ __forceinline__ A4 mm2q_a16(const short* __restrict__ Wf,
                                       const short* __restrict__ A0, const short* __restrict__ A1,
                                       int ldA, int mrow, int q, int l, A4 c) {
    static_assert(KS % 4 == 0, "KS must be a multiple of 4");
    const short* ap0 = A0 + mrow * ldA + q * 8;
    const short* ap1 = A1 + mrow * ldA + q * 8;
    const short* wp  = Wf + (size_t)l * 8;
#pragma unroll
    for (int kc = 0; kc < KS; kc += 4) {
        h16x8 fa0[4], fa1[4], fb0[4], fb1[4];
#pragma unroll
        for (int k = 0; k < 4; ++k) {
            fa0[k] = ld8h(ap0 + (kc + k) * 32);
            fa1[k] = ld8h(ap1 + (kc + k) * 32);
            fb0[k] = ld8h(wp + (size_t)(kc + k) * 512);
            fb1[k] = ld8h(wp + (size_t)(KS + kc + k) * 512);
        }
#pragma unroll
        for (int k = 0; k < 4; ++k) {
            c.p = MFMA16(fa0[k], fb0[k], c.p);
            c.r = MFMA16(fa1[k], fb0[k], c.r);
            c.q = MFMA16(fa0[k], fb1[k], c.q);
            c.s = MFMA16(fa1[k], fb1[k], c.s);
        }
    }
    return c;
}

// dual-graph, 2-tile matmul, fp32 A from LDS (converted per k-slice); burst
template<int KS>
__device__ __forceinline__ A4 mm2q_a32(const short* __restrict__ Wf,
                                       const float* __restrict__ A0, const float* __restrict__ A1,
                                       int ldA, int mrow, int q, int l, A4 c) {
    static_assert(KS % 4 == 0, "KS must be a multiple of 4");
    const float* ap0 = A0 + mrow * ldA + q * 8;
    const float* ap1 = A1 + mrow * ldA + q * 8;
    const short* wp  = Wf + (size_t)l * 8;
#pragma unroll
    for (int kc = 0; kc < KS; kc += 4) {
        h16x8 fa0[4], fa1[4], fb0[4], fb1[4];
#pragma unroll
        for (int k = 0; k < 4; ++k) {
            fa0[k] = cvt8(ap0 + (kc + k) * 32);
            fa1[k] = cvt8(ap1 + (kc + k) * 32);
            fb0[k] = ld8h(wp + (size_t)(kc + k) * 512);
            fb1[k] = ld8h(wp + (size_t)(KS + kc + k) * 512);
        }
#pragma unroll
        for (int k = 0; k < 4; ++k) {
            c.p = MFMA16(fa0[k], fb0[k], c.p);
            c.r = MFMA16(fa1[k], fb0[k], c.r);
            c.q = MFMA16(fa0[k], fb1[k], c.q);
            c.s = MFMA16(fa1[k], fb1[k], c.s);
        }
    }
    return c;
}

#define HLD 132   // Hf row stride (f32)
#define SLD 392   // staging row stride (fp16)

// store one graph's 2 tiles (by value) into staging LDS, rows >= 10 dropped
template<bool RELU>
__device__ __forceinline__ void st2(f32x4 u, f32x4 v, short* __restrict__ dst, int q, int c16) {
#pragma unroll
    for (int i = 0; i < 4; ++i) {
        int r = q * 4 + i;
        if (r < 10) {
            float a = u[i], b = v[i];
            if (RELU) { a = fmaxf(a, 0.f); b = fmaxf(b, 0.f); }
            dst[r * SLD + c16]      = f2hs(a);
            dst[r * SLD + 16 + c16] = f2hs(b);
        }
    }
}

// masked column-sum epilogue for ONE phi2 tile (by value)
__device__ __forceinline__ void colsum1(f32x4 v4, const float* __restrict__ hmf,
                                        const float* __restrict__ awf,
                                        short* __restrict__ rho, int tt, int q, int c16, int l) {
    float v0 = fmaxf(v4[0], 0.f), v1 = fmaxf(v4[1], 0.f);
    float v2 = fmaxf(v4[2], 0.f), v3 = fmaxf(v4[3], 0.f);
    float hp = hmf[q * 4 + 0] * v0 + hmf[q * 4 + 1] * v1 + hmf[q * 4 + 2] * v2 + hmf[q * 4 + 3] * v3;
    float ap = awf[q * 4 + 0] * v0 + awf[q * 4 + 1] * v1 + awf[q * 4 + 2] * v2 + awf[q * 4 + 3] * v3;
    hp += __shfl_xor(hp, 16); hp += __shfl_xor(hp, 32);
    ap += __shfl_xor(ap, 16); ap += __shfl_xor(ap, 32);
    if (l < 16) {
        rho[tt * 16 + l]       = f2hs(hp);
        rho[256 + tt * 16 + l] = f2hs(ap);
    }
}

// rho epilogue for ONE graph (by value)
__device__ __forceinline__ void rhoepi1(f32x4 t0, f32x4 t1, const float* __restrict__ r2w,
                                        int wv, int q, int c16, int l, float* __restrict__ dSg) {
    float d = 0.f;
    if (q == 0) {
        d = (fmaxf(t0[0], 0.f) - fmaxf(t0[1], 0.f)) * r2w[(wv * 2 + 0) * 16 + c16];
        d = fmaf(fmaxf(t1[0], 0.f) - fmaxf(t1[1], 0.f), r2w[(wv * 2 + 1) * 16 + c16], d);
    }
#pragma unroll
    for (int off = 32; off > 0; off >>= 1) d += __shfl_xor(d, off);
    if (l == 0) dSg[wv] = d;
}

// waves_per_eu(2,5): r9 proved this kills scratch at VGPR<=102 budget.
__global__ __attribute__((amdgpu_waves_per_eu(2, 5))) __launch_bounds__(256)
void gcn_main(const float* __restrict__ A, const float* __restrict__ X,
              const int* __restrict__ home_mask,
              const float* __restrict__ be1, const float* __restrict__ be2,
              const float* __restrict__ rgcn_b,
              const float* __restrict__ l1b, const float* __restrict__ l2b,
              const float* __restrict__ ln_g, const float* __restrict__ ln_b,
              const float* __restrict__ p1b, const float* __restrict__ p2b,
              const float* __restrict__ r1b, const float* __restrict__ r2w,
              const short* __restrict__ ws, float* __restrict__ out)
{
    const int b   = blockIdx.x;        // graph pair: graphs 2b, 2b+1
    const int tid = threadIdx.x;       // 0..255
    const int wv  = tid >> 6;          // wave 0..3
    const int l   = tid & 63;          // lane
    const int q   = l >> 4;
    const int c16 = l & 15;
    const int mrow = (c16 < 10) ? c16 : 9;

    // per-graph state (31.2 KB total)
    __shared__ __align__(16) float HfS[2][N_ * HLD];   // residual H, fp32
    __shared__ __align__(16) short StS[2][N_ * SLD];   // staging: HW0|HW1|HWr / LN|hidden / phi
    __shared__ __align__(16) short RhoS[2][512];       // [hs ; aws] fp16
    __shared__ float AsS[2][100];                      // signed A
    __shared__ float C0S[2][100], C1S[2][100];         // |A|·D0·M0^T etc (layer-invariant)
    __shared__ float invc0S[2][N_], invc1S[2][N_], rsAS[2][N_];
    __shared__ float hmfS[2][16], awfS[2][16];
    __shared__ float dS[8];

    // ---- phase 0: stage A (signed) + masks + embed1 ----
    if (tid < 200) {
        int g = tid / 100, e = tid - g * 100;
        AsS[g][e] = A[(size_t)(2 * b + g) * 100 + e];
    }
    if (tid < 32) {
        int g = tid >> 4, idx = tid & 15;
        float hm = 0.f, aw = 0.f;
        if (idx < 10) { hm = (float)home_mask[(2 * b + g) * N_ + idx]; aw = 1.f - hm; }
        hmfS[g][idx] = hm; awfS[g][idx] = aw;
    }
    {   // embed1: H1 = relu(X@We1 + be1) -> St[g][0:128]
        A4 c = a4init(be1 + wv * 32, c16);
        h16x8 a0 = cvt8(X + (size_t)(2 * b + 0) * (N_ * DIN_) + mrow * DIN_ + q * 8);
        h16x8 a1 = cvt8(X + (size_t)(2 * b + 1) * (N_ * DIN_) + mrow * DIN_ + q * 8);
        h16x8 b0 = ld8h(ws + WS_WE1 + ((size_t)(wv * 2 + 0) * 64 + l) * 8);
        h16x8 b1 = ld8h(ws + WS_WE1 + ((size_t)(wv * 2 + 1) * 64 + l) * 8);
        c.p = MFMA16(a0, b0, c.p);
        c.r = MFMA16(a1, b0, c.r);
        c.q = MFMA16(a0, b1, c.q);
        c.s = MFMA16(a1, b1, c.s);
        st2<true>(c.p, c.q, StS[0] + wv * 32, q, c16);
        st2<true>(c.r, c.s, StS[1] + wv * 32, q, c16);
    }
    __syncthreads();

    // ---- phase 1: invc + rsA (VALU) + embed2 (MFMA) ----
    if (tid < 20) {
        int g = tid / 10, j = tid - g * 10;
        float c1 = 0.f;
#pragma unroll
        for (int i = 0; i < 10; ++i) c1 += (AsS[g][i * 10 + j] > 0.f) ? 1.f : 0.f;
        invc1S[g][j] = 1.f / fmaxf(c1, 1.f);
        invc0S[g][j] = 1.f / fmaxf(10.f - c1, 1.f);
        float r = 0.f;
#pragma unroll
        for (int k = 0; k < 10; ++k) r += fabsf(AsS[g][j * 10 + k]);
        rsAS[g][j] = r;
    }
    {   // embed2: H = H1@We2 + be2 -> Hf (fp32)
        A4 c = a4init(be2 + wv * 32, c16);
        c = mm2q_a16<4>(ws + WS_WE2 + (size_t)wv * 4096, StS[0], StS[1], SLD, mrow, q, l, c);
#pragma unroll
        for (int i = 0; i < 4; ++i) {
            int r = q * 4 + i;
            if (r < 10) {
                HfS[0][r * HLD + wv * 32 + c16]      = c.p[i];
                HfS[0][r * HLD + wv * 32 + 16 + c16] = c.q[i];
                HfS[1][r * HLD + wv * 32 + c16]      = c.r[i];
                HfS[1][r * HLD + wv * 32 + 16 + c16] = c.s[i];
            }
        }
    }
    __syncthreads();

    // ---- phase 2: coefficient matrices (layer-invariant):
    //   agg[i] = sum_k C0[i,k]·HW0[k] + C1[i,k]·HW1[k] + |A[i,k]|·HWr[k] + rsA[i]·b
    if (tid < 200) {
        int g = tid / 100, e = tid - g * 100;
        int i = e / 10, k = e - i * 10;
        const float* As = AsS[g];
        float c0 = 0.f, c1 = 0.f;
#pragma unroll
        for (int j = 0; j < 10; ++j) {
            float aij = fabsf(As[i * 10 + j]);
            if (As[k * 10 + j] > 0.f) c1 += aij * invc1S[g][j];
            else                      c0 += aij * invc0S[g][j];
        }
        C0S[g][e] = c0; C1S[g][e] = c1;
    }
    __syncthreads();

    const v2f lg2 = *(const v2f*)(ln_g + 2 * l);
    const v2f lb2 = *(const v2f*)(ln_b + 2 * l);

    // ---- layers ----
    for (int ll = 0; ll < L_; ++ll) {
        // RGCN matmuls, 3 passes: HW0|HW1|HWr -> St[g][m*128 ..].
        // FULL unroll (r13): no barrier between passes; scheduler hoists
        // pass m+1's weight loads under pass m's MFMAs.
#pragma unroll
        for (int m = 0; m < 3; ++m) {
            const short* Wf;
            if      (m == 0) Wf = ws + WS_RGW + (size_t)(ll * 2 + 0) * 16384 + (size_t)wv * 4096;
            else if (m == 1) Wf = ws + WS_RGW + (size_t)(ll * 2 + 1) * 16384 + (size_t)wv * 4096;
            else             Wf = ws + WS_RGR + (size_t)ll * 16384 + (size_t)wv * 4096;
            A4 c = a4zero();
            c = mm2q_a32<4>(Wf, HfS[0], HfS[1], HLD, mrow, q, l, c);
            st2<false>(c.p, c.q, StS[0] + m * 128 + wv * 32, q, c16);
            st2<false>(c.r, c.s, StS[1] + m * 128 + wv * 32, q, c16);
        }
        __syncthreads();
        // combine + LN + relu (VALU): wave wv owns tasks t = wv+4s; named results
        {
            v2f rb2 = *(const v2f*)(rgcn_b + ll * D_ + 2 * l);
            auto lnTask = [&](int t) -> short2 {
                int g = (t >= 10) ? 1 : 0, i = t - g * 10;
                const short* St = StS[g];
                const float* C0 = C0S[g] + i * 10;
                const float* C1 = C1S[g] + i * 10;
                const float* As = AsS[g] + i * 10;
                v2f ag = splat2(rsAS[g][i]) * rb2;
#pragma unroll
                for (int j = 0; j < 10; ++j) {
                    short2 h0 = *(const short2*)(St + j * SLD + 2 * l);
                    short2 h1 = *(const short2*)(St + j * SLD + 128 + 2 * l);
                    short2 hr = *(const short2*)(St + j * SLD + 256 + 2 * l);
                    v2f v0; v0.x = hs2f(h0.x); v0.y = hs2f(h0.y);
                    v2f v1; v1.x = hs2f(h1.x); v1.y = hs2f(h1.y);
                    v2f vr; vr.x = hs2f(hr.x); vr.y = hs2f(hr.y);
                    ag = fma2(splat2(C0[j]), v0, ag);
                    ag = fma2(splat2(C1[j]), v1, ag);
                    ag = fma2(splat2(fabsf(As[j])), vr, ag);
                }
                float sm = ag.x + ag.y;
                float ss = fmaf(ag.x, ag.x, ag.y * ag.y);
#pragma unroll
                for (int off = 32; off > 0; off >>= 1) {
                    sm += __shfl_xor(sm, off);
                    ss += __shfl_xor(ss, off);
                }
                float mu   = sm * (1.f / 128.f);
                float var  = ss * (1.f / 128.f) - mu * mu;
                float rstd = rsqrtf(var + EPS_);
                v2f v = fma2((ag - splat2(mu)) * splat2(rstd), lg2, lb2);
                short2 o;
                o.x = f2hs(fmaxf(v.x, 0.f));
                o.y = f2hs(fmaxf(v.y, 0.f));
                return o;
            };
            short2 ln0 = lnTask(wv);
            short2 ln1 = lnTask(wv + 4);
            short2 ln2 = lnTask(wv + 8);
            short2 ln3 = lnTask(wv + 12);
            short2 ln4 = lnTask(wv + 16);
            __syncthreads();                   // all HW* reads done
            auto stTask = [&](int t, short2 v) {
                int g = (t >= 10) ? 1 : 0, i = t - g * 10;
                *(short2*)(StS[g] + i * SLD + 2 * l) = v;   // LNout -> cols 0:128
            };
            stTask(wv, ln0);
            stTask(wv + 4, ln1);
            stTask(wv + 8, ln2);
            stTask(wv + 12, ln3);
            stTask(wv + 16, ln4);
        }
        __syncthreads();
        // MLP1: relu(LNout @ l1w + l1b): reads St[0:128], writes St[128:256]
        {
            A4 c = a4init(l1b + ll * D_ + wv * 32, c16);
            c = mm2q_a16<4>(ws + WS_L1 + (size_t)ll * 16384 + (size_t)wv * 4096,
                            StS[0], StS[1], SLD, mrow, q, l, c);
            st2<true>(c.p, c.q, StS[0] + 128 + wv * 32, q, c16);
            st2<true>(c.r, c.s, StS[1] + 128 + wv * 32, q, c16);
        }
        __syncthreads();
        // MLP2: hidden @ l2w + l2b: reads St[128:256], Hf += result
        {
            A4 c = a4init(l2b + ll * D_ + wv * 32, c16);
            c = mm2q_a16<4>(ws + WS_L2 + (size_t)ll * 16384 + (size_t)wv * 4096,
                            StS[0] + 128, StS[1] + 128, SLD, mrow, q, l, c);
#pragma unroll
            for (int i = 0; i < 4; ++i) {
                int r = q * 4 + i;
                if (r < 10) {
                    HfS[0][r * HLD + wv * 32 + c16]      += c.p[i];
                    HfS[0][r * HLD + wv * 32 + 16 + c16] += c.q[i];
                    HfS[1][r * HLD + wv * 32 + c16]      += c.r[i];
                    HfS[1][r * HLD + wv * 32 + 16 + c16] += c.s[i];
                }
            }
        }
        __syncthreads();
    }

    // ---- phi1: relu(H @ p1w + p1b) -> St[g][0:256]; 2 passes of 2 tiles ----
#pragma unroll
    for (int half = 0; half < 2; ++half) {
        const int nt0 = 4 * wv + 2 * half;
        A4 c = a4init(p1b + nt0 * 16, c16);
        c = mm2q_a32<4>(ws + WS_P1 + (size_t)nt0 * 2048, HfS[0], HfS[1], HLD, mrow, q, l, c);
        st2<true>(c.p, c.q, StS[0] + nt0 * 16, q, c16);
        st2<true>(c.r, c.s, StS[1] + nt0 * 16, q, c16);
    }
    __syncthreads();
    // ---- phi2 + masked column sums -> RhoS[g]; 2 passes of 2 tiles ----
#pragma unroll
    for (int half = 0; half < 2; ++half) {
        const int nt0 = 4 * wv + 2 * half;
        A4 c = a4init(p2b + nt0 * 16, c16);
        c = mm2q_a16<8>(ws + WS_P2 + (size_t)nt0 * 4096, StS[0], StS[1], SLD, mrow, q, l, c);
        colsum1(c.p, hmfS[0], awfS[0], RhoS[0], nt0,     q, c16, l);
        colsum1(c.q, hmfS[0], awfS[0], RhoS[0], nt0 + 1, q, c16, l);
        colsum1(c.r, hmfS[1], awfS[1], RhoS[1], nt0,     q, c16, l);
        colsum1(c.s, hmfS[1], awfS[1], RhoS[1], nt0 + 1, q, c16, l);
    }
    __syncthreads();
    // ---- rho: relu([hs;aws] @ r1w + r1b) @ r2w; antisym difference ----
    {
        A4 c = a4init(r1b + wv * 32, c16);
        const int rr = (c16 < 2) ? c16 : 0;
        c = mm2q_a16<8>(ws + WS_R1 + (size_t)wv * 8192, RhoS[0], RhoS[1], 256, rr, q, l, c);
        rhoepi1(c.p, c.q, r2w, wv, q, c16, l, dS);       // graph 0
        rhoepi1(c.r, c.s, r2w, wv, q, c16, l, dS + 4);   // graph 1
    }
    __syncthreads();
    if (tid < 2)
        out[2 * b + tid] = 0.5f + 0.5f * tanhf(dS[tid * 4] + dS[tid * 4 + 1] +
                                               dS[tid * 4 + 2] + dS[tid * 4 + 3]);
}

extern "C" void kernel_launch(void* const* d_in, const int* in_sizes, int n_in,
                              void* d_out, int out_size, void* d_ws, size_t ws_size,
                              hipStream_t stream) {
    const float* A         = (const float*)d_in[0];
    const float* X         = (const float*)d_in[1];
    const int*   home_mask = (const int*)  d_in[2];
    const float* We1       = (const float*)d_in[3];
    const float* be1       = (const float*)d_in[4];
    const float* We2       = (const float*)d_in[5];
    const float* be2       = (const float*)d_in[6];
    const float* rgcn_w    = (const float*)d_in[7];
    const float* rgcn_root = (const float*)d_in[8];
    const float* rgcn_b    = (const float*)d_in[9];
    const float* l1w       = (const float*)d_in[10];
    const float* l1b       = (const float*)d_in[11];
    const float* l2w       = (const float*)d_in[12];
    const float* l2b       = (const float*)d_in[13];
    const float* ln_g      = (const float*)d_in[14];
    const float* ln_b      = (const float*)d_in[15];
    const float* p1w       = (const float*)d_in[16];
    const float* p1b       = (const float*)d_in[17];
    const float* p2w       = (const float*)d_in[18];
    const float* p2b       = (const float*)d_in[19];
    const float* r1w       = (const float*)d_in[20];
    const float* r1b       = (const float*)d_in[21];
    const float* r2w       = (const float*)d_in[22];

    short* ws = (short*)d_ws;

    prep_weights<<<194, 256, 0, stream>>>(We1, We2, rgcn_w, rgcn_root,
                                          l1w, l2w, p1w, p2w, r1w, ws);
    gcn_main<<<B_ / 2, 256, 0, stream>>>(A, X, home_mask, be1, be2, rgcn_b,
                                         l1b, l2b, ln_g, ln_b, p1b, p2b,
                                         r1b, r2w, ws, (float*)d_out);
}